// Round 4
// baseline (89.266 us; speedup 1.0000x reference)
//
#include <hip/hip_runtime.h>
#include <stdint.h>

typedef unsigned short u16;
typedef __attribute__((ext_vector_type(8))) __bf16 bf16x8;
typedef __attribute__((ext_vector_type(4))) float f32x4;

#define AS1 __attribute__((address_space(1)))
#define AS3 __attribute__((address_space(3)))

__device__ __forceinline__ u16 f2bf(float f) {
  uint32_t u = __builtin_bit_cast(uint32_t, f);
  u += 0x7FFFu + ((u >> 16) & 1u);   // RNE; inputs are finite
  return (u16)(u >> 16);
}
__device__ __forceinline__ void gload16(const void* g, void* l) {
  __builtin_amdgcn_global_load_lds((AS1 void*)g, (AS3 void*)l, 16, 0, 0);
}

// ---- fused prep:
//  blocks [0,4096):      x [4][2048][512] f32 -> x_bf (row-major bf16) AND x_t [4][512][2048] bf16
//  blocks [4096,4608):   w_qkv cols 512..1535 -> wk_t, wv_t (transposed bf16 [512][512])
//  blocks [4608,4864):   w_qkv cols 0..511   -> wq_bf (row-major bf16 [512][512])
__global__ __launch_bounds__(256) void prep2(const float* __restrict__ x,
                                             u16* __restrict__ x_bf, u16* __restrict__ x_t,
                                             const float* __restrict__ w_qkv,
                                             u16* __restrict__ wk_t, u16* __restrict__ wv_t,
                                             u16* __restrict__ wq_bf) {
  __shared__ u16 tile[32][33];
  const int bid = blockIdx.x;
  const int t = threadIdx.x;
  const int tx = t & 31, ty = t >> 5;
  if (bid < 4096) {
    int b = bid >> 10, tt = bid & 1023;
    int n0 = (tt & 63) * 32, i0 = (tt >> 6) * 32;
    const float* xb = x + (size_t)b * 2048 * 512;
    u16* xbf_b = x_bf + (size_t)b * 2048 * 512;
    u16* xt_b  = x_t  + (size_t)b * 512 * 2048;
    #pragma unroll
    for (int rr = ty; rr < 32; rr += 8) {
      u16 h = f2bf(xb[(size_t)(n0 + rr) * 512 + i0 + tx]);
      tile[rr][tx] = h;
      xbf_b[(size_t)(n0 + rr) * 512 + i0 + tx] = h;
    }
    __syncthreads();
    #pragma unroll
    for (int rr = ty; rr < 32; rr += 8)
      xt_b[(size_t)(i0 + rr) * 2048 + n0 + tx] = tile[tx][rr];
  } else if (bid < 4608) {
    int tb = bid - 4096;
    int which = tb >> 8, tt = tb & 255;
    int c0 = (tt & 15) * 32, r0 = (tt >> 4) * 32;
    int coff = 512 + which * 512;
    u16* wt = which ? wv_t : wk_t;
    #pragma unroll
    for (int rr = ty; rr < 32; rr += 8)
      tile[rr][tx] = f2bf(w_qkv[(size_t)(r0 + rr) * 1536 + coff + c0 + tx]);
    __syncthreads();
    #pragma unroll
    for (int rr = ty; rr < 32; rr += 8)
      wt[(size_t)(c0 + rr) * 512 + r0 + tx] = tile[tx][rr];
  } else {
    int cb = bid - 4608;
    int flat0 = cb * 1024 + t * 4;
    int r = flat0 >> 9, hd = flat0 & 511;
    float4 v = *(const float4*)(w_qkv + (size_t)r * 1536 + hd);
    ushort4 o;
    o.x = f2bf(v.x); o.y = f2bf(v.y); o.z = f2bf(v.z); o.w = f2bf(v.w);
    *(ushort4*)(wq_bf + (size_t)r * 512 + hd) = o;
  }
}

// ---- bf16 GEMM, m97 structure: 128xBN tile, 4 waves, BK=32, optional split-K ----
// z: bz = z/ksplit selects batch (A,Bt), k-window = (z%ksplit)*K .. +K; C slab = z.
// C[row,col] = sum_k A[row,kOff+k] * Bt[col,kOff+k]  (+bias). BN = NFRAG*32.
template<bool OUT_F32, bool BIAS, int NFRAG>
__global__ __launch_bounds__(256) void gemm_bt(
    const u16* __restrict__ A, int lda, long long strideA,
    const u16* __restrict__ Bt, int ldb, long long strideB,
    void* __restrict__ C, int ldc, long long strideC,
    const float* __restrict__ bias, int K, int ksplit)
{
  constexpr int BN = NFRAG * 32;
  const int bcol = blockIdx.x * BN;
  const int brow = blockIdx.y * 128;
  const int z = blockIdx.z;
  const int bz = z / ksplit;
  const int kOff = (z - bz * ksplit) * K;
  const u16* Ab = A + (size_t)bz * strideA;
  const u16* Bb = Bt + (size_t)bz * strideB;

  __shared__ u16 Asm[128 * 32];
  __shared__ u16 Bsm[BN * 32];

  const int tid = threadIdx.x;
  const int wid = tid >> 6;
  const int lane = tid & 63;
  const int fr = lane & 15, fq = lane >> 4;
  const int wr = wid >> 1, wc = wid & 1;
  const int skel = (lane & 3) * 8;        // k element within 32 (16B granules)

  f32x4 acc[4][NFRAG];
  #pragma unroll
  for (int m = 0; m < 4; ++m)
    #pragma unroll
    for (int n = 0; n < NFRAG; ++n)
      acc[m][n] = (f32x4)0.0f;

  for (int kt = 0; kt < K; kt += 32) {
    #pragma unroll
    for (int q = 0; q < 2; ++q) {
      int chunk = wid * 2 + q;            // 0..7, 16 rows each
      int row = chunk * 16 + (lane >> 2);
      gload16(Ab + (size_t)(brow + row) * lda + kOff + kt + skel, &Asm[chunk * 512]);
    }
    #pragma unroll
    for (int q = 0; q < BN / 64; ++q) {
      int chunk = wid * (BN / 64) + q;
      int row = chunk * 16 + (lane >> 2);
      gload16(Bb + (size_t)(bcol + row) * ldb + kOff + kt + skel, &Bsm[chunk * 512]);
    }
    __syncthreads();   // compiler drains vmcnt before s_barrier

    bf16x8 af[4], bg[NFRAG];
    #pragma unroll
    for (int m = 0; m < 4; ++m)
      af[m] = *(const bf16x8*)&Asm[(wr * 64 + m * 16 + fr) * 32 + fq * 8];
    #pragma unroll
    for (int n = 0; n < NFRAG; ++n)
      bg[n] = *(const bf16x8*)&Bsm[(wc * (NFRAG * 16) + n * 16 + fr) * 32 + fq * 8];
    #pragma unroll
    for (int m = 0; m < 4; ++m)
      #pragma unroll
      for (int n = 0; n < NFRAG; ++n)
        acc[m][n] = __builtin_amdgcn_mfma_f32_16x16x32_bf16(af[m], bg[n], acc[m][n], 0, 0, 0);
    __syncthreads();
  }

  #pragma unroll
  for (int m = 0; m < 4; ++m) {
    #pragma unroll
    for (int n = 0; n < NFRAG; ++n) {
      #pragma unroll
      for (int j = 0; j < 4; ++j) {
        int row = brow + wr * 64 + m * 16 + fq * 4 + j;
        int col = bcol + wc * (NFRAG * 16) + n * 16 + fr;
        float v = acc[m][n][j];
        if constexpr (OUT_F32) {
          if constexpr (BIAS) v += bias[col];
          ((float*)C)[(size_t)z * strideC + (size_t)row * ldc + col] = v;
        } else {
          ((u16*)C)[(size_t)z * strideC + (size_t)row * ldc + col] = f2bf(v);
        }
      }
    }
  }
}

// ---- G_bf[b][i][j] = bf16( sum_s Gpart[b*4+s][i][j] ), vectorized ----
__global__ __launch_bounds__(256) void reduce_g(const float4* __restrict__ Gpart4,
                                                ushort4* __restrict__ G4) {
  int i4 = blockIdx.x * 256 + threadIdx.x;     // < 4*65536
  int b = i4 >> 16, off = i4 & 65535;
  float4 s;
  s.x = 0.f; s.y = 0.f; s.z = 0.f; s.w = 0.f;
  #pragma unroll
  for (int p = 0; p < 4; ++p) {
    float4 g = Gpart4[((size_t)(b * 4 + p)) * 65536 + off];
    s.x += g.x; s.y += g.y; s.z += g.z; s.w += g.w;
  }
  ushort4 o;
  o.x = f2bf(s.x); o.y = f2bf(s.y); o.z = f2bf(s.z); o.w = f2bf(s.w);
  G4[i4] = o;
}

// ---- Pt[b][c][h*64+d] = scale * sum_e Mfull[b][h64+d][h64+e] * w_out[h64+e][c] ----
__global__ __launch_bounds__(256) void make_pt3(const float* __restrict__ Mfull,
                                                const float* __restrict__ w_out,
                                                u16* __restrict__ Pt, float scale) {
  const int ct = blockIdx.x;      // 0..7
  const int bh = blockIdx.y;      // 0..31
  const int b = bh >> 3, h = bh & 7;
  const int t = threadIdx.x;
  __shared__ float Msm[64 * 64];
  {
    const float* base = Mfull + (size_t)b * 262144 + (size_t)(h * 64) * 512 + h * 64;
    float4* dst = (float4*)Msm;
    #pragma unroll
    for (int r = 0; r < 4; ++r) {
      int flat = t + r * 256;              // float4 index; row=flat>>4, c4=flat&15
      int row = flat >> 4, c4 = flat & 15;
      dst[flat] = *(const float4*)(base + (size_t)row * 512 + c4 * 4);
    }
  }
  __syncthreads();
  const int c = ct * 64 + (t & 63);
  const int d0 = (t >> 6) * 16;
  float acc[16];
  #pragma unroll
  for (int j = 0; j < 16; ++j) acc[j] = 0.f;
  const float* wcol = w_out + (size_t)h * 64 * 512 + c;
  #pragma unroll 4
  for (int e = 0; e < 64; ++e) {
    float w = wcol[(size_t)e * 512];
    #pragma unroll
    for (int j = 0; j < 16; ++j)
      acc[j] += Msm[(d0 + j) * 64 + e] * w;
  }
  ushort4 ov[4];
  #pragma unroll
  for (int r = 0; r < 4; ++r) {
    ov[r].x = f2bf(acc[r * 4 + 0] * scale);
    ov[r].y = f2bf(acc[r * 4 + 1] * scale);
    ov[r].z = f2bf(acc[r * 4 + 2] * scale);
    ov[r].w = f2bf(acc[r * 4 + 3] * scale);
  }
  ushort4* dst = (ushort4*)(Pt + (size_t)b * 262144 + (size_t)c * 512 + h * 64 + d0);
  #pragma unroll
  for (int r = 0; r < 4; ++r) dst[r] = ov[r];
}

extern "C" void kernel_launch(void* const* d_in, const int* in_sizes, int n_in,
                              void* d_out, int out_size, void* d_ws, size_t ws_size,
                              hipStream_t stream) {
  const float* x     = (const float*)d_in[0];   // [4,2048,512]
  const float* w_qkv = (const float*)d_in[1];   // [512,1536]
  const float* w_out = (const float*)d_in[2];   // [512,512]
  const float* b_out = (const float*)d_in[3];   // [512]
  float* out = (float*)d_out;                   // [4,2048,512] f32
  char* ws = (char*)d_ws;
  const long long MB = 1ll << 20;

  u16*   x_bf   = (u16*)(ws);                    // 8 MiB  [4][2048][512] bf16
  u16*   x_t    = (u16*)(ws + 8 * MB);           // 8 MiB  [4][512][2048] bf16
  u16*   wk_t   = (u16*)(ws + 16 * MB);          // 0.5 MiB [512][512]  (Wk^T)
  u16*   wv_t   = (u16*)(ws + 16 * MB + 524288); // 0.5 MiB [512][512]  (Wv^T)
  u16*   wq_bf  = (u16*)(ws + 17 * MB);          // 0.5 MiB [512][512]  (Wq row-major)
  float* Gpart  = (float*)(ws + 18 * MB);        // 16 MiB [16][512][512] f32
  u16*   G_bf   = (u16*)(ws + 34 * MB);          // 2 MiB  [4][512][512] bf16 (symmetric)
  u16*   T1t    = (u16*)(ws + 36 * MB);          // 2 MiB  [4][512][512] bf16 (G@Wv)^T
  float* Mfull  = (float*)(ws + 38 * MB);        // 4 MiB  [4][512][512] f32 (Wk^T G Wv)
  u16*   Pt     = (u16*)(ws + 42 * MB);          // 2 MiB  [4][512][512] bf16 (P^T)
  u16*   Weff_t = (u16*)(ws + 44 * MB);          // 2 MiB  [4][512][512] bf16 (W_eff^T)

  // 1) all input conversions/transposes (one launch)
  prep2<<<dim3(4864), dim3(256), 0, stream>>>(x, x_bf, x_t, w_qkv, wk_t, wv_t, wq_bf);
  // 2) Gram: Gpart[b*4+s] = x_t[b] @ x_t[b]^T over k-window s  (M=N=512, K=2048/4)
  gemm_bt<true, false, 2><<<dim3(8, 4, 16), dim3(256), 0, stream>>>(
      x_t, 2048, 512ll * 2048, x_t, 2048, 512ll * 2048, Gpart, 512, 262144ll, nullptr, 512, 4);
  // 3) reduce split-K partials -> bf16 G
  reduce_g<<<dim3(1024), dim3(256), 0, stream>>>((const float4*)Gpart, (ushort4*)G_bf);
  // 4) T1t[b] = (G_b @ Wv)^T = Wv^T G_b  (G symmetric): A=wv_t, Bt=G_b
  gemm_bt<false, false, 2><<<dim3(8, 4, 4), dim3(256), 0, stream>>>(
      wv_t, 512, 0ll, G_bf, 512, 262144ll, T1t, 512, 262144ll, nullptr, 512, 1);
  // 5) Mfull[b] = Wk^T @ T1 : C[d,e] = sum_i wk_t[d][i]*T1t[e][i]  (diag blocks = M_h)
  gemm_bt<true, false, 2><<<dim3(8, 4, 4), dim3(256), 0, stream>>>(
      wk_t, 512, 0ll, T1t, 512, 262144ll, Mfull, 512, 262144ll, nullptr, 512, 1);
  // 6) Pt[b] = (scale * blockdiag(M) @ W_out)^T
  make_pt3<<<dim3(8, 32), dim3(256), 0, stream>>>(Mfull, w_out, Pt, 0.125f / 2048.0f);
  // 7) Weff_t[b][c][r] = sum_hd Pt[b][c][hd] * Wq[r][hd]  ( = W_eff^T )
  gemm_bt<false, false, 2><<<dim3(8, 4, 4), dim3(256), 0, stream>>>(
      Pt, 512, 262144ll, wq_bf, 512, 0ll, Weff_t, 512, 262144ll, nullptr, 512, 1);
  // 8) out[b] = x_bf[b] @ W_eff + b_out  (M=2048, N=512, K=512), f32
  gemm_bt<true, true, 2><<<dim3(8, 16, 4), dim3(256), 0, stream>>>(
      x_bf, 512, 2048ll * 512, Weff_t, 512, 262144ll, out, 512, 2048ll * 512, b_out, 512, 1);
}

// Round 5
// 81.688 us; speedup vs baseline: 1.0928x; 1.0928x over previous
//
#include <hip/hip_runtime.h>
#include <stdint.h>

typedef unsigned short u16;
typedef __attribute__((ext_vector_type(8))) __bf16 bf16x8;
typedef __attribute__((ext_vector_type(8))) unsigned short u16x8;
typedef __attribute__((ext_vector_type(4))) float f32x4;

#define AS1 __attribute__((address_space(1)))
#define AS3 __attribute__((address_space(3)))

__device__ __forceinline__ u16 f2bf(float f) {
  uint32_t u = __builtin_bit_cast(uint32_t, f);
  u += 0x7FFFu + ((u >> 16) & 1u);   // RNE; inputs are finite
  return (u16)(u >> 16);
}
__device__ __forceinline__ float bf2f(u16 h) {
  uint32_t u = ((uint32_t)h) << 16;
  return __builtin_bit_cast(float, u);
}
__device__ __forceinline__ void gload16(const void* g, void* l) {
  __builtin_amdgcn_global_load_lds((AS1 void*)g, (AS3 void*)l, 16, 0, 0);
}

// ---- fused prep:
//  blocks [0,4096):      x f32 -> x_bf bf16 (plain vectorized)
//  blocks [4096,4608):   w_qkv cols 512..1535 -> wkv_t [1024][512] bf16 (transposed)
//  blocks [4608,4864):   w_qkv cols 0..511   -> wq_bf [512][512] bf16 (row-major)
__global__ __launch_bounds__(256) void prep(const float* __restrict__ x,
                                            u16* __restrict__ x_bf,
                                            const float* __restrict__ w_qkv,
                                            u16* __restrict__ wkv_t,
                                            u16* __restrict__ wq_bf) {
  __shared__ u16 tile[32][33];
  const int bid = blockIdx.x;
  const int t = threadIdx.x;
  if (bid < 4096) {
    int i = bid * 256 + t;
    float4 v = ((const float4*)x)[i];
    ushort4 o;
    o.x = f2bf(v.x); o.y = f2bf(v.y); o.z = f2bf(v.z); o.w = f2bf(v.w);
    ((ushort4*)x_bf)[i] = o;
  } else if (bid < 4608) {
    int tb = bid - 4096;                  // 0..511: c-tile over 1024 (32), r-tile over 512 (16)
    int c0 = (tb & 31) * 32, r0 = (tb >> 5) * 32;
    int tx = t & 31, ty = t >> 5;
    #pragma unroll
    for (int rr = ty; rr < 32; rr += 8)
      tile[rr][tx] = f2bf(w_qkv[(size_t)(r0 + rr) * 1536 + 512 + c0 + tx]);
    __syncthreads();
    #pragma unroll
    for (int rr = ty; rr < 32; rr += 8)
      wkv_t[(size_t)(c0 + rr) * 512 + r0 + tx] = tile[tx][rr];
  } else {
    int cb = bid - 4608;                  // 0..255
    int flat0 = cb * 1024 + t * 4;
    int r = flat0 >> 9, hd = flat0 & 511;
    float4 v = *(const float4*)(w_qkv + (size_t)r * 1536 + hd);
    ushort4 o;
    o.x = f2bf(v.x); o.y = f2bf(v.y); o.z = f2bf(v.z); o.w = f2bf(v.w);
    *(ushort4*)(wq_bf + (size_t)r * 512 + hd) = o;
  }
}

// ---- bf16 GEMM, m97 structure: 128xBN tile, 4 waves, BK=32 ----
// C[row,col] = sum_k A[row,k] * Bt[col,k]  (+bias). BN = NFRAG*32.
template<bool OUT_F32, bool BIAS, int NFRAG>
__global__ __launch_bounds__(256) void gemm_bt(
    const u16* __restrict__ A, int lda, long long strideA,
    const u16* __restrict__ Bt, int ldb, long long strideB,
    void* __restrict__ C, int ldc, long long strideC,
    const float* __restrict__ bias, int K)
{
  constexpr int BN = NFRAG * 32;
  const int bcol = blockIdx.x * BN;
  const int brow = blockIdx.y * 128;
  const int bz = blockIdx.z;
  const u16* Ab = A + (size_t)bz * strideA;
  const u16* Bb = Bt + (size_t)bz * strideB;

  __shared__ u16 Asm[128 * 32];
  __shared__ u16 Bsm[BN * 32];

  const int tid = threadIdx.x;
  const int wid = tid >> 6;
  const int lane = tid & 63;
  const int fr = lane & 15, fq = lane >> 4;
  const int wr = wid >> 1, wc = wid & 1;
  const int skel = (lane & 3) * 8;        // k element within 32 (16B granules)

  f32x4 acc[4][NFRAG];
  #pragma unroll
  for (int m = 0; m < 4; ++m)
    #pragma unroll
    for (int n = 0; n < NFRAG; ++n)
      acc[m][n] = (f32x4)0.0f;

  for (int kt = 0; kt < K; kt += 32) {
    #pragma unroll
    for (int q = 0; q < 2; ++q) {
      int chunk = wid * 2 + q;            // 0..7, 16 rows each
      int row = chunk * 16 + (lane >> 2);
      gload16(Ab + (size_t)(brow + row) * lda + kt + skel, &Asm[chunk * 512]);
    }
    #pragma unroll
    for (int q = 0; q < BN / 64; ++q) {
      int chunk = wid * (BN / 64) + q;
      int row = chunk * 16 + (lane >> 2);
      gload16(Bb + (size_t)(bcol + row) * ldb + kt + skel, &Bsm[chunk * 512]);
    }
    __syncthreads();   // compiler drains vmcnt before s_barrier

    bf16x8 af[4], bg[NFRAG];
    #pragma unroll
    for (int m = 0; m < 4; ++m)
      af[m] = *(const bf16x8*)&Asm[(wr * 64 + m * 16 + fr) * 32 + fq * 8];
    #pragma unroll
    for (int n = 0; n < NFRAG; ++n)
      bg[n] = *(const bf16x8*)&Bsm[(wc * (NFRAG * 16) + n * 16 + fr) * 32 + fq * 8];
    #pragma unroll
    for (int m = 0; m < 4; ++m)
      #pragma unroll
      for (int n = 0; n < NFRAG; ++n)
        acc[m][n] = __builtin_amdgcn_mfma_f32_16x16x32_bf16(af[m], bg[n], acc[m][n], 0, 0, 0);
    __syncthreads();
  }

  #pragma unroll
  for (int m = 0; m < 4; ++m) {
    #pragma unroll
    for (int n = 0; n < NFRAG; ++n) {
      #pragma unroll
      for (int j = 0; j < 4; ++j) {
        int row = brow + wr * 64 + m * 16 + fq * 4 + j;
        int col = bcol + wc * (NFRAG * 16) + n * 16 + fr;
        float v = acc[m][n][j];
        if constexpr (OUT_F32) {
          if constexpr (BIAS) v += bias[col];
          ((float*)C)[(size_t)bz * strideC + (size_t)row * ldc + col] = v;
        } else {
          ((u16*)C)[(size_t)bz * strideC + (size_t)row * ldc + col] = f2bf(v);
        }
      }
    }
  }
}

// ---- per-(b,h) partial K^T V over a 128-row N-slice of kv[8192][1024] ----
#define KTV_SPLIT 16
__device__ __forceinline__ void ktv_load(const u16* __restrict__ base, int n0, int h, int t,
                                         u16x8& a, u16x8& b) {
  int row0 = t >> 4, part0 = t & 15;
  int col0 = (part0 < 8) ? (h * 64 + part0 * 8) : (512 + h * 64 + (part0 - 8) * 8);
  a = *(const u16x8*)(base + (size_t)(n0 + row0) * 1024 + col0);
  int idx1 = 256 + t;
  int row1 = idx1 >> 4, part1 = idx1 & 15;
  int col1 = (part1 < 8) ? (h * 64 + part1 * 8) : (512 + h * 64 + (part1 - 8) * 8);
  b = *(const u16x8*)(base + (size_t)(n0 + row1) * 1024 + col1);
}

__global__ __launch_bounds__(256) void ktv_partial(const u16* __restrict__ kv,
                                                   float* __restrict__ Mpart) {
  const int s = blockIdx.x;    // 0..15
  const int bh = blockIdx.y;   // 0..31
  const int b = bh >> 3, h = bh & 7;
  const int t = threadIdx.x;
  __shared__ float smem[4096];           // Kf[32][64] | Vf[32][64]; later Msm[64][64]
  float* Kf = smem;
  float* Vf = smem + 2048;

  const int nsub = t >> 6;               // wave id: n-subset within chunk
  const int slot = t & 63;
  const int d0 = (slot >> 2) * 4;
  const int e0 = (slot & 3) * 16;

  float acc[4][16];
  #pragma unroll
  for (int i = 0; i < 4; ++i)
    #pragma unroll
    for (int j = 0; j < 16; ++j) acc[i][j] = 0.f;

  const u16* base = kv + (size_t)b * 2048 * 1024;
  const int row0 = t >> 4, part0 = t & 15;
  const int idx1 = 256 + t, row1 = idx1 >> 4, part1 = idx1 & 15;
  float* dst0 = (part0 < 8) ? &Kf[row0 * 64 + part0 * 8] : &Vf[row0 * 64 + (part0 - 8) * 8];
  float* dst1 = (part1 < 8) ? &Kf[row1 * 64 + part1 * 8] : &Vf[row1 * 64 + (part1 - 8) * 8];

  u16x8 cur0, cur1, nxt0, nxt1;
  ktv_load(base, s * 128, h, t, cur0, cur1);

  for (int c = 0; c < 4; ++c) {
    __syncthreads();                     // previous chunk's compute done
    #pragma unroll
    for (int j = 0; j < 8; ++j) dst0[j] = bf2f(cur0[j]);
    #pragma unroll
    for (int j = 0; j < 8; ++j) dst1[j] = bf2f(cur1[j]);
    if (c < 3) ktv_load(base, s * 128 + (c + 1) * 32, h, t, nxt0, nxt1);  // T14
    __syncthreads();
    #pragma unroll
    for (int nn = 0; nn < 8; ++nn) {
      int n = nsub * 8 + nn;
      f32x4 kq = *(const f32x4*)&Kf[n * 64 + d0];
      f32x4 v0 = *(const f32x4*)&Vf[n * 64 + e0];
      f32x4 v1 = *(const f32x4*)&Vf[n * 64 + e0 + 4];
      f32x4 v2 = *(const f32x4*)&Vf[n * 64 + e0 + 8];
      f32x4 v3 = *(const f32x4*)&Vf[n * 64 + e0 + 12];
      #pragma unroll
      for (int i = 0; i < 4; ++i) {
        float ki = kq[i];
        #pragma unroll
        for (int j = 0; j < 4; ++j) {
          acc[i][j]      += ki * v0[j];
          acc[i][4 + j]  += ki * v1[j];
          acc[i][8 + j]  += ki * v2[j];
          acc[i][12 + j] += ki * v3[j];
        }
      }
    }
    cur0 = nxt0; cur1 = nxt1;
  }

  __syncthreads();                       // all compute done; smem reusable as Msm
  float* Msm = smem;
  #pragma unroll
  for (int p = 0; p < 4; ++p) {
    if (nsub == p) {
      #pragma unroll
      for (int i = 0; i < 4; ++i)
        #pragma unroll
        for (int j = 0; j < 16; ++j) {
          float* q = &Msm[(d0 + i) * 64 + e0 + j];
          *q = (p == 0) ? acc[i][j] : (*q + acc[i][j]);
        }
    }
    __syncthreads();
  }
  float4* d4 = (float4*)(Mpart + ((size_t)bh * KTV_SPLIT + s) * 4096);
  const float4* s4 = (const float4*)smem;
  #pragma unroll
  for (int r = 0; r < 4; ++r) d4[t + r * 256] = s4[t + r * 256];
}

// ---- M[bh][d][e] = scale * sum_p Mpart[bh][p][d][e] ----
__global__ __launch_bounds__(256) void reduce_m(const float* __restrict__ Mpart,
                                                float* __restrict__ M, float scale) {
  int i = blockIdx.x * 256 + threadIdx.x;      // 0 .. 32*4096-1
  int bh = i >> 12;
  int off = i & 4095;
  const float* src = Mpart + ((size_t)bh * KTV_SPLIT) * 4096 + off;
  float s = 0.f;
  #pragma unroll
  for (int p = 0; p < KTV_SPLIT; ++p) s += src[(size_t)p * 4096];
  M[i] = s * scale;
}

// ---- Pt[b][c][h*64+d] = sum_e M[bh][d][e] * w_out[h*64+e][c], bf16 ----
__global__ __launch_bounds__(256) void make_pt2(const float* __restrict__ M,
                                                const float* __restrict__ w_out,
                                                u16* __restrict__ Pt) {
  const int ct = blockIdx.x;      // 0..7
  const int bh = blockIdx.y;      // 0..31
  const int b = bh >> 3, h = bh & 7;
  const int t = threadIdx.x;
  __shared__ float Msm[64 * 64];
  {
    const float4* src = (const float4*)(M + (size_t)bh * 4096);
    float4* dst = (float4*)Msm;
    #pragma unroll
    for (int r = 0; r < 4; ++r) dst[t + r * 256] = src[t + r * 256];
  }
  __syncthreads();
  const int c = ct * 64 + (t & 63);
  const int d0 = (t >> 6) * 16;
  float acc[16];
  #pragma unroll
  for (int j = 0; j < 16; ++j) acc[j] = 0.f;
  const float* wcol = w_out + (size_t)h * 64 * 512 + c;
  #pragma unroll 4
  for (int e = 0; e < 64; ++e) {
    float w = wcol[(size_t)e * 512];
    #pragma unroll
    for (int j = 0; j < 16; ++j)
      acc[j] += Msm[(d0 + j) * 64 + e] * w;
  }
  ushort4 ov[4];
  #pragma unroll
  for (int r = 0; r < 4; ++r) {
    ov[r].x = f2bf(acc[r * 4 + 0]);
    ov[r].y = f2bf(acc[r * 4 + 1]);
    ov[r].z = f2bf(acc[r * 4 + 2]);
    ov[r].w = f2bf(acc[r * 4 + 3]);
  }
  ushort4* dst = (ushort4*)(Pt + (size_t)b * 262144 + (size_t)c * 512 + h * 64 + d0);
  #pragma unroll
  for (int r = 0; r < 4; ++r) dst[r] = ov[r];
}

extern "C" void kernel_launch(void* const* d_in, const int* in_sizes, int n_in,
                              void* d_out, int out_size, void* d_ws, size_t ws_size,
                              hipStream_t stream) {
  const float* x     = (const float*)d_in[0];   // [4,2048,512]
  const float* w_qkv = (const float*)d_in[1];   // [512,1536]
  const float* w_out = (const float*)d_in[2];   // [512,512]
  const float* b_out = (const float*)d_in[3];   // [512]
  float* out = (float*)d_out;                   // [4,2048,512] f32
  char* ws = (char*)d_ws;
  const long long MB = 1ll << 20;

  u16*   x_bf   = (u16*)(ws);                    // 8 MiB  [8192][512] bf16
  u16*   wkv_t  = (u16*)(ws + 8 * MB);           // 1 MiB  [1024][512] bf16 (W_kv^T)
  u16*   wq_bf  = (u16*)(ws + 9 * MB);           // 0.5 MiB [512][512] bf16 (Wq row-major)
  u16*   kv     = (u16*)(ws + 10 * MB);          // 16 MiB [8192][1024] bf16
  float* Mpart  = (float*)(ws + 26 * MB);        // 8 MiB  [32][16][64][64] f32
  float* M      = (float*)(ws + 34 * MB);        // 0.5 MiB [32][64][64] f32
  u16*   Pt     = (u16*)(ws + 35 * MB);          // 2 MiB  [4][512][512] bf16 (P^T per b)
  u16*   Weff_t = (u16*)(ws + 37 * MB);          // 2 MiB  [4][512][512] bf16 (W_eff^T)

  // 1) conversions (one launch)
  prep<<<dim3(4864), dim3(256), 0, stream>>>(x, x_bf, w_qkv, wkv_t, wq_bf);
  // 2) kv = x @ W_kv   (M=8192, N=1024, K=512), bf16 out
  gemm_bt<false, false, 4><<<dim3(8, 64, 1), dim3(256), 0, stream>>>(
      x_bf, 512, 0ll, wkv_t, 512, 0ll, kv, 1024, 0ll, nullptr, 512);
  // 3) partial K^T V per (b,h)
  ktv_partial<<<dim3(KTV_SPLIT, 32), dim3(256), 0, stream>>>(kv, Mpart);
  // 4) reduce partials (scale folded)
  reduce_m<<<dim3(512), dim3(256), 0, stream>>>(Mpart, M, 0.125f / 2048.0f);
  // 5) Pt = (M @ W_out)^T per (b,h)
  make_pt2<<<dim3(8, 32), dim3(256), 0, stream>>>(M, w_out, Pt);
  // 6) Weff_t[b][c][r] = sum_hd Pt[b][c][hd] * Wq[r][hd]   (W_eff = Wq @ P)
  gemm_bt<false, false, 2><<<dim3(8, 4, 4), dim3(256), 0, stream>>>(
      Pt, 512, 262144ll, wq_bf, 512, 0ll, Weff_t, 512, 262144ll, nullptr, 512);
  // 7) out[b] = x_bf[b] @ W_eff + b_out  (M=2048, N=512, K=512), f32
  gemm_bt<true, true, 2><<<dim3(8, 16, 4), dim3(256), 0, stream>>>(
      x_bf, 512, 2048ll * 512, Weff_t, 512, 262144ll, out, 512, 2048ll * 512, b_out, 512);
}

// Round 6
// 63.851 us; speedup vs baseline: 1.3980x; 1.2794x over previous
//
#include <hip/hip_runtime.h>
#include <stdint.h>

typedef unsigned short u16;
typedef __attribute__((ext_vector_type(8))) __bf16 bf16x8;
typedef __attribute__((ext_vector_type(8))) unsigned short u16x8;
typedef __attribute__((ext_vector_type(4))) float f32x4;

#define AS1 __attribute__((address_space(1)))
#define AS3 __attribute__((address_space(3)))

__device__ __forceinline__ u16 f2bf(float f) {
  uint32_t u = __builtin_bit_cast(uint32_t, f);
  u += 0x7FFFu + ((u >> 16) & 1u);   // RNE; inputs are finite
  return (u16)(u >> 16);
}
__device__ __forceinline__ float bf2f(u16 h) {
  uint32_t u = ((uint32_t)h) << 16;
  return __builtin_bit_cast(float, u);
}
__device__ __forceinline__ void gload16(const void* g, void* l) {
  __builtin_amdgcn_global_load_lds((AS1 void*)g, (AS3 void*)l, 16, 0, 0);
}

// ---- fused: x f32->bf16 (blocks 0..4095) + w_qkv transpose (blocks 4096..4863) ----
__global__ __launch_bounds__(256) void prep(const float4* __restrict__ x,
                                            ushort4* __restrict__ x_bf,
                                            const float* __restrict__ w,
                                            u16* __restrict__ wt) {
  __shared__ u16 tile[32][33];
  const int bid = blockIdx.x;
  if (bid < 4096) {
    int i = bid * 256 + threadIdx.x;
    float4 v = x[i];
    ushort4 o;
    o.x = f2bf(v.x); o.y = f2bf(v.y); o.z = f2bf(v.z); o.w = f2bf(v.w);
    x_bf[i] = o;
  } else {
    int tb = bid - 4096;                 // 0..767 over [512][1536]
    int c0 = (tb % 48) * 32, r0 = (tb / 48) * 32;
    int tx = threadIdx.x & 31, ty = threadIdx.x >> 5;
    #pragma unroll
    for (int rr = ty; rr < 32; rr += 8)
      tile[rr][tx] = f2bf(w[(size_t)(r0 + rr) * 1536 + c0 + tx]);
    __syncthreads();
    #pragma unroll
    for (int rr = ty; rr < 32; rr += 8)
      wt[(size_t)(c0 + rr) * 512 + r0 + tx] = tile[tx][rr];
  }
}

// ---- bf16 GEMM: 128xBN tile, 4 waves, BK=64, T2 LDS swizzle, T1 XCD swizzle ----
// C[row,col] = sum_k A[row,k] * Bt[col,k]  (+bias). BN = NFRAG*32. K%64==0.
// Staging: global source col pre-swizzled (scol), LDS linear (rule #21);
// reads XOR the same involution. Grid x*y*z must be divisible by 8.
template<bool OUT_F32, bool BIAS, int NFRAG>
__global__ __launch_bounds__(256) void gemm_bt64(
    const u16* __restrict__ A, int lda, long long strideA,
    const u16* __restrict__ Bt, int ldb, long long strideB,
    void* __restrict__ C, int ldc, long long strideC,
    const float* __restrict__ bias, int K)
{
  constexpr int BN = NFRAG * 32;
  // T1: bijective XCD-chunked remap of the linear hw block id
  const int nwgx = gridDim.x, nwgy = gridDim.y;
  const int nwg = nwgx * nwgy * gridDim.z;
  const int hw = blockIdx.x + nwgx * (blockIdx.y + nwgy * blockIdx.z);
  const int cpx = nwg >> 3;
  const int swz = (hw & 7) * cpx + (hw >> 3);
  const int bx = swz % nwgx;
  const int tmp = swz / nwgx;
  const int by = tmp % nwgy;
  const int bz = tmp / nwgy;

  const int bcol = bx * BN;
  const int brow = by * 128;
  const u16* Ab = A + (size_t)bz * strideA;
  const u16* Bb = Bt + (size_t)bz * strideB;

  __shared__ u16 Asm[128 * 64];
  __shared__ u16 Bsm[BN * 64];

  const int tid = threadIdx.x;
  const int wid = tid >> 6;
  const int lane = tid & 63;
  const int fr = lane & 15, fq = lane >> 4;
  const int wr = wid >> 1, wc = wid & 1;
  const int srow = lane >> 3;                 // 0..7 within an 8-row segment
  const int scol = ((lane & 7) ^ srow) * 8;   // T2 pre-swizzled source column
  const int xr = (fr & 7) * 8;                // read-side XOR (row&7)*8

  f32x4 acc[4][NFRAG];
  #pragma unroll
  for (int m = 0; m < 4; ++m)
    #pragma unroll
    for (int n = 0; n < NFRAG; ++n)
      acc[m][n] = (f32x4)0.0f;

  for (int kt = 0; kt < K; kt += 64) {
    #pragma unroll
    for (int q = 0; q < 4; ++q) {
      int seg = wid * 4 + q;                  // 0..15, 8 rows each
      int row = seg * 8 + srow;
      gload16(Ab + (size_t)(brow + row) * lda + kt + scol, &Asm[seg * 512]);
    }
    #pragma unroll
    for (int q = 0; q < NFRAG; ++q) {
      int seg = wid * NFRAG + q;              // 0..BN/8-1
      int row = seg * 8 + srow;
      gload16(Bb + (size_t)(bcol + row) * ldb + kt + scol, &Bsm[seg * 512]);
    }
    __syncthreads();   // compiler drains vmcnt before s_barrier

    #pragma unroll
    for (int kk = 0; kk < 2; ++kk) {
      bf16x8 af[4], bg[NFRAG];
      #pragma unroll
      for (int m = 0; m < 4; ++m)
        af[m] = *(const bf16x8*)&Asm[(wr * 64 + m * 16 + fr) * 64 + ((kk * 32 + fq * 8) ^ xr)];
      #pragma unroll
      for (int n = 0; n < NFRAG; ++n)
        bg[n] = *(const bf16x8*)&Bsm[(wc * (NFRAG * 16) + n * 16 + fr) * 64 + ((kk * 32 + fq * 8) ^ xr)];
      #pragma unroll
      for (int m = 0; m < 4; ++m)
        #pragma unroll
        for (int n = 0; n < NFRAG; ++n)
          acc[m][n] = __builtin_amdgcn_mfma_f32_16x16x32_bf16(af[m], bg[n], acc[m][n], 0, 0, 0);
    }
    __syncthreads();
  }

  #pragma unroll
  for (int m = 0; m < 4; ++m) {
    #pragma unroll
    for (int n = 0; n < NFRAG; ++n) {
      #pragma unroll
      for (int j = 0; j < 4; ++j) {
        int row = brow + wr * 64 + m * 16 + fq * 4 + j;
        int col = bcol + wc * (NFRAG * 16) + n * 16 + fr;
        float v = acc[m][n][j];
        if constexpr (OUT_F32) {
          if constexpr (BIAS) v += bias[col];
          ((float*)C)[(size_t)bz * strideC + (size_t)row * ldc + col] = v;
        } else {
          ((u16*)C)[(size_t)bz * strideC + (size_t)row * ldc + col] = f2bf(v);
        }
      }
    }
  }
}

// ---- per-(b,h) partial K^T V over a 128-row N-slice of qkv[8192][1536] ----
#define KTV_SPLIT 16
__device__ __forceinline__ void ktv_load(const u16* __restrict__ base, int n0, int h, int t,
                                         u16x8& a, u16x8& b) {
  int row0 = t >> 4, part0 = t & 15;
  int col0 = (part0 < 8) ? (512 + h * 64 + part0 * 8) : (1024 + h * 64 + (part0 - 8) * 8);
  a = *(const u16x8*)(base + (size_t)(n0 + row0) * 1536 + col0);
  int idx1 = 256 + t;
  int row1 = idx1 >> 4, part1 = idx1 & 15;
  int col1 = (part1 < 8) ? (512 + h * 64 + part1 * 8) : (1024 + h * 64 + (part1 - 8) * 8);
  b = *(const u16x8*)(base + (size_t)(n0 + row1) * 1536 + col1);
}

__global__ __launch_bounds__(256) void ktv_partial(const u16* __restrict__ qkv,
                                                   float* __restrict__ Mpart) {
  const int s = blockIdx.x;    // 0..15
  const int bh = blockIdx.y;   // 0..31
  const int b = bh >> 3, h = bh & 7;
  const int t = threadIdx.x;
  __shared__ float smem[4096];           // Kf[32][64] | Vf[32][64]; later Msm[64][64]
  float* Kf = smem;
  float* Vf = smem + 2048;

  const int nsub = t >> 6;               // wave id: n-subset within chunk
  const int slot = t & 63;
  const int d0 = (slot >> 2) * 4;
  const int e0 = (slot & 3) * 16;

  float acc[4][16];
  #pragma unroll
  for (int i = 0; i < 4; ++i)
    #pragma unroll
    for (int j = 0; j < 16; ++j) acc[i][j] = 0.f;

  const u16* base = qkv + (size_t)b * 2048 * 1536;
  const int row0 = t >> 4, part0 = t & 15;
  const int idx1 = 256 + t, row1 = idx1 >> 4, part1 = idx1 & 15;
  float* dst0 = (part0 < 8) ? &Kf[row0 * 64 + part0 * 8] : &Vf[row0 * 64 + (part0 - 8) * 8];
  float* dst1 = (part1 < 8) ? &Kf[row1 * 64 + part1 * 8] : &Vf[row1 * 64 + (part1 - 8) * 8];

  u16x8 cur0, cur1, nxt0, nxt1;
  ktv_load(base, s * 128, h, t, cur0, cur1);

  for (int c = 0; c < 4; ++c) {
    __syncthreads();                     // previous chunk's compute done
    #pragma unroll
    for (int j = 0; j < 8; ++j) dst0[j] = bf2f(cur0[j]);
    #pragma unroll
    for (int j = 0; j < 8; ++j) dst1[j] = bf2f(cur1[j]);
    if (c < 3) ktv_load(base, s * 128 + (c + 1) * 32, h, t, nxt0, nxt1);  // T14
    __syncthreads();
    #pragma unroll
    for (int nn = 0; nn < 8; ++nn) {
      int n = nsub * 8 + nn;
      f32x4 kq = *(const f32x4*)&Kf[n * 64 + d0];
      f32x4 v0 = *(const f32x4*)&Vf[n * 64 + e0];
      f32x4 v1 = *(const f32x4*)&Vf[n * 64 + e0 + 4];
      f32x4 v2 = *(const f32x4*)&Vf[n * 64 + e0 + 8];
      f32x4 v3 = *(const f32x4*)&Vf[n * 64 + e0 + 12];
      #pragma unroll
      for (int i = 0; i < 4; ++i) {
        float ki = kq[i];
        #pragma unroll
        for (int j = 0; j < 4; ++j) {
          acc[i][j]      += ki * v0[j];
          acc[i][4 + j]  += ki * v1[j];
          acc[i][8 + j]  += ki * v2[j];
          acc[i][12 + j] += ki * v3[j];
        }
      }
    }
    cur0 = nxt0; cur1 = nxt1;
  }

  __syncthreads();                       // all compute done; smem reusable as Msm
  float* Msm = smem;
  #pragma unroll
  for (int p = 0; p < 4; ++p) {
    if (nsub == p) {
      #pragma unroll
      for (int i = 0; i < 4; ++i)
        #pragma unroll
        for (int j = 0; j < 16; ++j) {
          float* q = &Msm[(d0 + i) * 64 + e0 + j];
          *q = (p == 0) ? acc[i][j] : (*q + acc[i][j]);
        }
    }
    __syncthreads();
  }
  float4* d4 = (float4*)(Mpart + ((size_t)bh * KTV_SPLIT + s) * 4096);
  const float4* s4 = (const float4*)smem;
  #pragma unroll
  for (int r = 0; r < 4; ++r) d4[t + r * 256] = s4[t + r * 256];
}

// ---- M[bh][d][e] = scale * sum_p Mpart[bh][p][d][e] ----
__global__ __launch_bounds__(256) void reduce_m(const float* __restrict__ Mpart,
                                                float* __restrict__ M, float scale) {
  int i = blockIdx.x * 256 + threadIdx.x;      // 0 .. 32*4096-1
  int bh = i >> 12;
  int off = i & 4095;
  const float* src = Mpart + ((size_t)bh * KTV_SPLIT) * 4096 + off;
  float s = 0.f;
  #pragma unroll
  for (int p = 0; p < KTV_SPLIT; ++p) s += src[(size_t)p * 4096];
  M[i] = s * scale;
}

// ---- Pt[b][c][h*64+d] = sum_e M[bh][d][e] * w_out[h*64+e][c], bf16 ----
__global__ __launch_bounds__(256) void make_pt2(const float* __restrict__ M,
                                                const float* __restrict__ w_out,
                                                u16* __restrict__ Pt) {
  const int ct = blockIdx.x;      // 0..7
  const int bh = blockIdx.y;      // 0..31
  const int b = bh >> 3, h = bh & 7;
  const int t = threadIdx.x;
  __shared__ float Msm[64 * 64];
  {
    const float4* src = (const float4*)(M + (size_t)bh * 4096);
    float4* dst = (float4*)Msm;
    #pragma unroll
    for (int r = 0; r < 4; ++r) dst[t + r * 256] = src[t + r * 256];
  }
  __syncthreads();
  const int c = ct * 64 + (t & 63);
  const int d0 = (t >> 6) * 16;
  float acc[16];
  #pragma unroll
  for (int j = 0; j < 16; ++j) acc[j] = 0.f;
  const float* wcol = w_out + (size_t)h * 64 * 512 + c;
  #pragma unroll 4
  for (int e = 0; e < 64; ++e) {
    float w = wcol[(size_t)e * 512];
    #pragma unroll
    for (int j = 0; j < 16; ++j)
      acc[j] += Msm[(d0 + j) * 64 + e] * w;
  }
  ushort4 ov[4];
  #pragma unroll
  for (int r = 0; r < 4; ++r) {
    ov[r].x = f2bf(acc[r * 4 + 0]);
    ov[r].y = f2bf(acc[r * 4 + 1]);
    ov[r].z = f2bf(acc[r * 4 + 2]);
    ov[r].w = f2bf(acc[r * 4 + 3]);
  }
  ushort4* dst = (ushort4*)(Pt + (size_t)b * 262144 + (size_t)c * 512 + h * 64 + d0);
  #pragma unroll
  for (int r = 0; r < 4; ++r) dst[r] = ov[r];
}

extern "C" void kernel_launch(void* const* d_in, const int* in_sizes, int n_in,
                              void* d_out, int out_size, void* d_ws, size_t ws_size,
                              hipStream_t stream) {
  const float* x     = (const float*)d_in[0];   // [4,2048,512]
  const float* w_qkv = (const float*)d_in[1];   // [512,1536]
  const float* w_out = (const float*)d_in[2];   // [512,512]
  const float* b_out = (const float*)d_in[3];   // [512]
  float* out = (float*)d_out;                   // [4,2048,512] f32
  char* ws = (char*)d_ws;
  const long long MB = 1ll << 20;

  u16*   x_bf   = (u16*)(ws);                    // 8 MiB  [8192][512] bf16 (dead after GEMM1)
  u16*   wqkv_t = (u16*)(ws + 8 * MB);           // 1.5 MiB [1536][512] bf16 (w_qkv^T)
  u16*   qkv    = (u16*)(ws + 10 * MB);          // 24 MiB [8192][1536] bf16
  float* Mpart  = (float*)(ws + 34 * MB);        // 8 MiB  [32][16][64][64] f32
  float* M      = (float*)(ws);                  // 0.5 MiB [32][64][64] f32 (reuses x_bf)
  u16*   Pt     = (u16*)(ws + 42 * MB);          // 2 MiB  [4][512][512] bf16 (P^T per b)

  // 1) x -> bf16 and w_qkv -> transposed bf16 (fused launch)
  prep<<<dim3(4096 + 768), dim3(256), 0, stream>>>(
      (const float4*)x, (ushort4*)x_bf, w_qkv, wqkv_t);
  // 2) qkv = x @ w_qkv   (M=8192, N=1536, K=512), bf16 out; BK=64 + T1/T2
  gemm_bt64<false, false, 4><<<dim3(12, 64, 1), dim3(256), 0, stream>>>(
      x_bf, 512, 0ll, wqkv_t, 512, 0ll, qkv, 1536, 0ll, nullptr, 512);
  // 3) partial K^T V per (b,h)
  ktv_partial<<<dim3(KTV_SPLIT, 32), dim3(256), 0, stream>>>(qkv, Mpart);
  // 4) reduce partials (x_bf region is dead now)
  reduce_m<<<dim3(512), dim3(256), 0, stream>>>(Mpart, M, 0.125f / 2048.0f);
  // 5) Pt = (M @ W_out)^T per (b,h)
  make_pt2<<<dim3(8, 32), dim3(256), 0, stream>>>(M, w_out, Pt);
  // 6) out = Q_cat @ P + b_out  (per b: M=2048, N=512, K=512), f32 out, 128x64 tile
  gemm_bt64<true, true, 2><<<dim3(8, 16, 4), dim3(256), 0, stream>>>(
      qkv, 1536, 2048ll * 1536, Pt, 512, 262144ll, out, 512, 2048ll * 512, b_out, 512);
}